// Round 4
// baseline (279.281 us; speedup 1.0000x reference)
//
#include <hip/hip_runtime.h>

#define IMG_W 512
#define IMG_H 512
#define NPLANES 48        // 16 * 3
#define NPIX 12582912.0   // 16*3*512*512
#define NBLOCKS 768       // 8 col-groups x 2 x 48

// Each thread: one image column x 64-row strip, streaming top->bottom.
// Ring buffer (5 fields x 11 rows) in registers, statically indexed via
// 11-unrolled row loop. No LDS in the dataflow.
__global__ __launch_bounds__(256) void ssim_stream_kernel(
    const float* __restrict__ pred,
    const float* __restrict__ label,
    float* __restrict__ partial)
{
    const int tid   = threadIdx.x;
    const int cg    = blockIdx.x;                 // 64-col group, 0..7
    const int col   = cg * 64 + (tid & 63);
    const int strip = blockIdx.y * 4 + (tid >> 6); // 0..7 (64 rows each)
    const int oy    = strip * 64;
    const int plane = blockIdx.z;
    const float* __restrict__ xp = pred  + (size_t)plane * (IMG_W * IMG_H);
    const float* __restrict__ yp = label + (size_t)plane * (IMG_W * IMG_H);

    // Gaussian weights (sigma=1.5, K=11), normalized.
    float w[11];
    {
        float s = 0.f;
        #pragma unroll
        for (int i = 0; i < 11; ++i) {
            float d = (float)(i - 5);
            w[i] = expf(-d * d / 4.5f);
            s += w[i];
        }
        float inv = 1.0f / s;
        #pragma unroll
        for (int i = 0; i < 11; ++i) w[i] *= inv;
    }

    const bool edge = (cg == 0) || (cg == 7);   // block-uniform
    const int  c0   = col - 5;
    int   cc[11];
    float mf[11];
    #pragma unroll
    for (int j = 0; j < 11; ++j) {
        int c = c0 + j;
        cc[j] = min(max(c, 0), IMG_W - 1);
        mf[j] = ((unsigned)c < (unsigned)IMG_W) ? 1.0f : 0.0f;
    }

    float ring[5][11];   // [field][row % 11], all indices compile-time
    float lsum = 0.f;

    for (int rr = 0; rr < 7; ++rr) {
        #pragma unroll
        for (int p = 0; p < 11; ++p) {
            const int r = rr * 11 + p;       // ext row 0..73 (74 = 64 + 10)
            if (r < 74) {
                const int gr = oy - 5 + r;   // wave-uniform
                float hx = 0.f, hy = 0.f, hxx = 0.f, hyy = 0.f, hxy = 0.f;
                if ((unsigned)gr < (unsigned)IMG_H) {
                    const float* __restrict__ xr = xp + gr * IMG_W;
                    const float* __restrict__ yr = yp + gr * IMG_W;
                    if (edge) {
                        #pragma unroll
                        for (int j = 0; j < 11; ++j) {
                            float xv = xr[cc[j]] * mf[j];
                            float yv = yr[cc[j]] * mf[j];
                            float wj = w[j];
                            hx  += wj * xv;
                            hy  += wj * yv;
                            hxx += wj * xv * xv;
                            hyy += wj * yv * yv;
                            hxy += wj * xv * yv;
                        }
                    } else {
                        #pragma unroll
                        for (int j = 0; j < 11; ++j) {
                            float xv = xr[c0 + j];
                            float yv = yr[c0 + j];
                            float wj = w[j];
                            hx  += wj * xv;
                            hy  += wj * yv;
                            hxx += wj * xv * xv;
                            hyy += wj * yv * yv;
                            hxy += wj * xv * yv;
                        }
                    }
                }
                ring[0][p] = hx;
                ring[1][p] = hy;
                ring[2][p] = hxx;
                ring[3][p] = hyy;
                ring[4][p] = hxy;

                if (r >= 10) {
                    // output local row = r - 10; ring pos of row r-10+k is (p+1+k)%11
                    float mu1 = 0.f, mu2 = 0.f, cxx = 0.f, cyy = 0.f, cxy = 0.f;
                    #pragma unroll
                    for (int k = 0; k < 11; ++k) {
                        const int kk = (p + 1 + k) % 11;   // compile-time
                        float wk = w[k];
                        mu1 += wk * ring[0][kk];
                        mu2 += wk * ring[1][kk];
                        cxx += wk * ring[2][kk];
                        cyy += wk * ring[3][kk];
                        cxy += wk * ring[4][kk];
                    }
                    float mu1s = mu1 * mu1, mu2s = mu2 * mu2, mu12 = mu1 * mu2;
                    float s1  = cxx - mu1s;
                    float s2  = cyy - mu2s;
                    float s12 = cxy - mu12;
                    const float C1 = 1e-4f, C2 = 9e-4f;
                    float num = (2.f * mu12 + C1) * (2.f * s12 + C2);
                    float den = (mu1s + mu2s + C1) * (s1 + s2 + C2);
                    lsum += num * __builtin_amdgcn_rcpf(den);
                }
            }
        }
    }

    // ---- Block reduction -> one float partial per block ----
    #pragma unroll
    for (int off = 32; off > 0; off >>= 1)
        lsum += __shfl_down(lsum, off, 64);

    __shared__ float wsum[4];
    if ((tid & 63) == 0) wsum[tid >> 6] = lsum;
    __syncthreads();
    if (tid == 0) {
        int bid = (blockIdx.z * 2 + blockIdx.y) * 8 + blockIdx.x;
        partial[bid] = wsum[0] + wsum[1] + wsum[2] + wsum[3];
    }
}

__global__ __launch_bounds__(256) void ssim_finalize_kernel(
    const float* __restrict__ partial, float* __restrict__ out)
{
    double s = 0.0;
    for (int i = threadIdx.x; i < NBLOCKS; i += 256) s += (double)partial[i];
    #pragma unroll
    for (int off = 32; off > 0; off >>= 1) s += __shfl_down(s, off, 64);
    __shared__ double ws[4];
    if ((threadIdx.x & 63) == 0) ws[threadIdx.x >> 6] = s;
    __syncthreads();
    if (threadIdx.x == 0)
        out[0] = 1.0f - (float)((ws[0] + ws[1] + ws[2] + ws[3]) / NPIX);
}

extern "C" void kernel_launch(void* const* d_in, const int* in_sizes, int n_in,
                              void* d_out, int out_size, void* d_ws, size_t ws_size,
                              hipStream_t stream) {
    const float* pred  = (const float*)d_in[0];
    const float* label = (const float*)d_in[1];
    float* out = (float*)d_out;
    float* partial = (float*)d_ws;   // NBLOCKS floats, fully overwritten every call

    dim3 grid(8, 2, NPLANES);        // 8 col-groups x 2 strip-groups x 48 planes
    ssim_stream_kernel<<<grid, 256, 0, stream>>>(pred, label, partial);
    ssim_finalize_kernel<<<1, 256, 0, stream>>>(partial, out);
}

// Round 5
// 213.474 us; speedup vs baseline: 1.3083x; 1.3083x over previous
//
#include <hip/hip_runtime.h>

#define IMG_W 512
#define IMG_H 512
#define NPLANES 48         // 16 * 3
#define NPIX 12582912.0    // 16*3*512*512
#define ST 64              // words per (field,column) slot: 16 blocks x 4 rows
#define FSZ (32 * ST)      // words per field = 2048
#define NBLOCKS (16*16*48) // 12288

// LDS layout: element (field f, tile col c, ext row r) lives at
//   f*FSZ + c*ST + 4*((r>>2) ^ (c>>2)) + (r&3)
// XOR block-swizzle makes both the scalar writes (8g x 8r lanes -> 2/bank)
// and the float4 reads (each bank exactly 8 words/instr) conflict-free,
// while keeping every float4 16B-aligned.

__global__ __launch_bounds__(256) void ssim_fused_kernel(
    const float* __restrict__ pred,
    const float* __restrict__ label,
    float* __restrict__ partial)
{
    __shared__ float hT[5 * FSZ];   // 40 KB

    // Normalized 11-tap Gaussian, sigma=1.5 (precomputed, symmetric).
    const float w[11] = { 0.00102838f, 0.00759876f, 0.03600077f, 0.10936069f,
                          0.21300554f, 0.26601173f, 0.21300554f, 0.10936069f,
                          0.03600077f, 0.00759876f, 0.00102838f };

    const int tid = threadIdx.x;
    const int ox = blockIdx.x * 32;
    const int oy = blockIdx.y * 32;
    const int plane = blockIdx.z;
    const float* __restrict__ xp = pred  + (size_t)plane * (IMG_W * IMG_H);
    const float* __restrict__ yp = label + (size_t)plane * (IMG_W * IMG_H);

    // ---- Horizontal pass: 42 ext rows x 8 groups of 4 cols = 336 tasks ----
    const bool xInterior = (blockIdx.x != 0) && (blockIdx.x != (IMG_W / 32 - 1));
    for (int i = tid; i < 336; i += 256) {
        int r  = i >> 3;          // ext row 0..41
        int g  = i & 7;           // col group 0..7
        int gy = oy - 5 + r;
        int c0 = ox + g * 4;      // first output col of this group (global)

        float bx_[24], by_[24];
        bool rowok = ((unsigned)gy < (unsigned)IMG_H);
        if (!rowok) {
            #pragma unroll
            for (int j = 0; j < 24; ++j) { bx_[j] = 0.f; by_[j] = 0.f; }
        } else if (xInterior) {
            const float4* px4 = reinterpret_cast<const float4*>(xp + gy * IMG_W + (c0 - 8));
            const float4* py4 = reinterpret_cast<const float4*>(yp + gy * IMG_W + (c0 - 8));
            #pragma unroll
            for (int j = 0; j < 6; ++j) {
                float4 a = px4[j];
                float4 b = py4[j];
                bx_[4*j+0] = a.x; bx_[4*j+1] = a.y; bx_[4*j+2] = a.z; bx_[4*j+3] = a.w;
                by_[4*j+0] = b.x; by_[4*j+1] = b.y; by_[4*j+2] = b.z; by_[4*j+3] = b.w;
            }
        } else {
            #pragma unroll
            for (int j = 0; j < 24; ++j) {
                int col = c0 - 8 + j;
                bool ok = ((unsigned)col < (unsigned)IMG_W);
                bx_[j] = ok ? xp[gy * IMG_W + col] : 0.f;
                by_[j] = ok ? yp[gy * IMG_W + col] : 0.f;
            }
        }

        float a0[4] = {0,0,0,0}, a1[4] = {0,0,0,0}, a2[4] = {0,0,0,0},
              a3[4] = {0,0,0,0}, a4[4] = {0,0,0,0};
        // output o taps window cols j = o+3 .. o+13
        #pragma unroll
        for (int j = 3; j <= 16; ++j) {
            float xv = bx_[j], yv = by_[j];
            float xx = xv * xv, yy = yv * yv, xy = xv * yv;
            #pragma unroll
            for (int o = 0; o < 4; ++o) {
                int k = j - 3 - o;
                if (k >= 0 && k <= 10) {
                    float wk = w[k];
                    a0[o] += wk * xv;
                    a1[o] += wk * yv;
                    a2[o] += wk * xx;
                    a3[o] += wk * yy;
                    a4[o] += wk * xy;
                }
            }
        }

        // Swizzled scalar writes: one base + 20 immediate offsets.
        int wb = g * (4 * ST) + ((((r >> 2) ^ g) << 2) | (r & 3));
        #pragma unroll
        for (int o = 0; o < 4; ++o) {
            hT[wb + o*ST + 0*FSZ] = a0[o];
            hT[wb + o*ST + 1*FSZ] = a1[o];
            hT[wb + o*ST + 2*FSZ] = a2[o];
            hT[wb + o*ST + 3*FSZ] = a3[o];
            hT[wb + o*ST + 4*FSZ] = a4[o];
        }
    }
    __syncthreads();

    // ---- Vertical pass: 32 cols x 8 row-groups of 4 = 256 tasks ----
    float lsum = 0.f;
    {
        int c  = tid & 31;
        int rg = tid >> 5;        // output rows 4*rg .. 4*rg+3
        int sc = c >> 2;
        int cb = c * ST;

        // Swizzled block addresses for ext-row blocks rg..rg+3 (shared by all fields)
        int d0 = cb + 4 * ((rg + 0) ^ sc);
        int d1 = cb + 4 * ((rg + 1) ^ sc);
        int d2 = cb + 4 * ((rg + 2) ^ sc);
        int d3 = cb + 4 * ((rg + 3) ^ sc);

        float m[5][4];
        #pragma unroll
        for (int f = 0; f < 5; ++f) {
            float4 v0 = *reinterpret_cast<const float4*>(&hT[f*FSZ + d0]);
            float4 v1 = *reinterpret_cast<const float4*>(&hT[f*FSZ + d1]);
            float4 v2 = *reinterpret_cast<const float4*>(&hT[f*FSZ + d2]);
            float4 v3 = *reinterpret_cast<const float4*>(&hT[f*FSZ + d3]);
            float vv[16] = { v0.x, v0.y, v0.z, v0.w,
                             v1.x, v1.y, v1.z, v1.w,
                             v2.x, v2.y, v2.z, v2.w,
                             v3.x, v3.y, v3.z, v3.w };
            #pragma unroll
            for (int o = 0; o < 4; ++o) {
                float s = 0.f;
                #pragma unroll
                for (int k = 0; k < 11; ++k) s += w[k] * vv[o + k];
                m[f][o] = s;
            }
        }

        #pragma unroll
        for (int o = 0; o < 4; ++o) {
            float mu1 = m[0][o], mu2 = m[1][o];
            float mu1s = mu1 * mu1, mu2s = mu2 * mu2, mu12 = mu1 * mu2;
            float s1  = m[2][o] - mu1s;
            float s2  = m[3][o] - mu2s;
            float s12 = m[4][o] - mu12;
            const float C1 = 1e-4f, C2 = 9e-4f;
            float num = (2.f * mu12 + C1) * (2.f * s12 + C2);
            float den = (mu1s + mu2s + C1) * (s1 + s2 + C2);
            lsum += num * __builtin_amdgcn_rcpf(den);
        }
    }

    // ---- Block reduction -> one float partial per block ----
    #pragma unroll
    for (int off = 32; off > 0; off >>= 1)
        lsum += __shfl_down(lsum, off, 64);

    __shared__ float wsum[4];
    if ((tid & 63) == 0) wsum[tid >> 6] = lsum;
    __syncthreads();
    if (tid == 0) {
        int bid = (blockIdx.z * gridDim.y + blockIdx.y) * gridDim.x + blockIdx.x;
        partial[bid] = wsum[0] + wsum[1] + wsum[2] + wsum[3];
    }
}

__global__ __launch_bounds__(1024) void ssim_finalize_kernel(
    const float* __restrict__ partial, float* __restrict__ out)
{
    double s = 0.0;
    for (int i = threadIdx.x; i < NBLOCKS; i += 1024) s += (double)partial[i];
    #pragma unroll
    for (int off = 32; off > 0; off >>= 1) s += __shfl_down(s, off, 64);
    __shared__ double ws[16];
    if ((threadIdx.x & 63) == 0) ws[threadIdx.x >> 6] = s;
    __syncthreads();
    if (threadIdx.x == 0) {
        double t = 0.0;
        #pragma unroll
        for (int k = 0; k < 16; ++k) t += ws[k];
        out[0] = 1.0f - (float)(t / NPIX);
    }
}

extern "C" void kernel_launch(void* const* d_in, const int* in_sizes, int n_in,
                              void* d_out, int out_size, void* d_ws, size_t ws_size,
                              hipStream_t stream) {
    const float* pred  = (const float*)d_in[0];
    const float* label = (const float*)d_in[1];
    float* out = (float*)d_out;
    float* partial = (float*)d_ws;   // NBLOCKS floats, fully overwritten every call

    dim3 grid(IMG_W / 32, IMG_H / 32, NPLANES);
    ssim_fused_kernel<<<grid, 256, 0, stream>>>(pred, label, partial);
    ssim_finalize_kernel<<<1, 1024, 0, stream>>>(partial, out);
}